// Round 6
// baseline (686.112 us; speedup 1.0000x reference)
//
#include <hip/hip_runtime.h>

// GraphConv SpMM: out[row[e], :] += edge_vals[e] * x[col[e], :]
// N = 500000, E = 8000000, D = 64, fp32.
//
// Round 10: MLP-widened reduce (8 edges/iter via ds_read_b128 of inv).
//   1. hist: bucket = row>>10 (489 buckets), 1024-thr blocks, NT row reads
//   2. single-block scan -> bucket run starts
//   3. bin: 1024-thr blocks, NT col/val reads, packs (lrow10<<19|col, val)
//   4. sort_reduce: 4 sub-blocks per medium bucket. Ballot-filter own
//      256-row slice into ed[] (48 KB), per-row hist/scan -> inv[] perm,
//      then register-accumulate reduce, NOW 8-wide: one 16B LDS read
//      gives 8 inv indices -> 8 ed broadcasts -> 8 x-gathers in flight
//      -> 8 FMA chains. Round-9 counters showed VGPR=24 / 45% BW /
//      19% VALU: 3-deep LDS->LDS->global chain fully exposed, compiler
//      refused to pipeline the 4-deep scalar-inv version.
//      __launch_bounds__(1024,8) keeps <=64 VGPR -> 2 blocks/CU.

#define D_FEAT 64
#define RPM 1024               // rows per medium bucket
#define RPB 256                // rows per sub-bucket (acc tile)
#define BKT_SHIFT 10
#define MAX_BKT 512
#define TILE 32768             // hist/bin tile (1024 threads * EPT)
#define EPT 32
#define NTHR 1024
#define CAP 6144               // max staged edges per sub-bucket

typedef float vf4 __attribute__((ext_vector_type(4)));

// ---------------- bucket histogram ----------------
__global__ __launch_bounds__(NTHR)
void hist_kernel(const int* __restrict__ row, int* __restrict__ cnt_g,
                 int n_edges, int kb) {
    __shared__ int cnt[MAX_BKT];
    for (int i = threadIdx.x; i < kb; i += NTHR) cnt[i] = 0;
    __syncthreads();
    int base = blockIdx.x * TILE;
#pragma unroll
    for (int k = 0; k < EPT; k++) {
        int e = base + k * NTHR + threadIdx.x;
        if (e < n_edges)
            atomicAdd(&cnt[__builtin_nontemporal_load(&row[e]) >> BKT_SHIFT], 1);
    }
    __syncthreads();
    for (int i = threadIdx.x; i < kb; i += NTHR) {
        int c = cnt[i];
        if (c) atomicAdd(&cnt_g[i], c);
    }
}

// ---------------- single-block scan over kb buckets ----------------
__global__ __launch_bounds__(256)
void scan_kernel(const int* __restrict__ cnt_g, int* __restrict__ start,
                 int* __restrict__ gcursor, int kb) {
    __shared__ int sums[256];
    int vals[8];
    int base = threadIdx.x * 8;
    int s = 0;
#pragma unroll
    for (int i = 0; i < 8; i++) {
        int idx = base + i;
        int v = (idx < kb) ? cnt_g[idx] : 0;
        s += v;
        vals[i] = s;
    }
    sums[threadIdx.x] = s;
    __syncthreads();
    for (int off = 1; off < 256; off <<= 1) {
        int t = (threadIdx.x >= off) ? sums[threadIdx.x - off] : 0;
        __syncthreads();
        sums[threadIdx.x] += t;
        __syncthreads();
    }
    int toff = (threadIdx.x > 0) ? sums[threadIdx.x - 1] : 0;
#pragma unroll
    for (int i = 0; i < 8; i++) {
        int idx = base + i;
        if (idx < kb) {
            int incl = vals[i] + toff;
            int v = vals[i] - (i ? vals[i - 1] : 0);
            start[idx + 1] = incl;
            gcursor[idx] = incl - v;
        }
    }
    if (threadIdx.x == 0) start[0] = 0;
}

// ---------------- bin edges into bucket runs ----------------
__global__ __launch_bounds__(NTHR)
void bin_kernel(const int* __restrict__ row, const int* __restrict__ col,
                const float* __restrict__ val,
                int* __restrict__ gcursor, int2* __restrict__ packed,
                int n_edges, int kb) {
    __shared__ int cnt[MAX_BKT];
    __shared__ int base_s[MAX_BKT];
    for (int i = threadIdx.x; i < kb; i += NTHR) cnt[i] = 0;
    __syncthreads();
    int tbase = blockIdx.x * TILE;
#pragma unroll
    for (int k = 0; k < EPT; k++) {
        int e = tbase + k * NTHR + threadIdx.x;
        if (e < n_edges) atomicAdd(&cnt[row[e] >> BKT_SHIFT], 1);
    }
    __syncthreads();
    for (int i = threadIdx.x; i < kb; i += NTHR) {
        int c = cnt[i];
        base_s[i] = c ? atomicAdd(&gcursor[i], c) : 0;
        cnt[i] = 0;
    }
    __syncthreads();
#pragma unroll
    for (int k = 0; k < EPT; k++) {
        int e = tbase + k * NTHR + threadIdx.x;
        if (e < n_edges) {
            int r = __builtin_nontemporal_load(&row[e]);   // L2-hot re-read
            int c = __builtin_nontemporal_load(&col[e]);
            float v = __builtin_nontemporal_load(&val[e]);
            int b = r >> BKT_SHIFT;
            int rank = atomicAdd(&cnt[b], 1);
            packed[base_s[b] + rank] =
                make_int2(((r & (RPM - 1)) << 19) | c, __float_as_int(v));
        }
    }
}

// ---------------- fused per-sub-bucket filter + sort + reduce ----------------
__global__ __launch_bounds__(NTHR, 8)
void sort_reduce(const float* __restrict__ x, const int2* __restrict__ packed,
                 const int* __restrict__ start, float* __restrict__ out,
                 int n_nodes) {
    __shared__ int2 ed[CAP];                                   // 48 KB
    __shared__ unsigned short inv[CAP] __attribute__((aligned(16)));  // 12 KB
    __shared__ int cnt[RPB];
    __shared__ int sc[RPB];
    __shared__ int cur[RPB];
    __shared__ int ns_sh;

    const int tid = threadIdx.x;
    const int bm = blockIdx.x >> 2;        // medium bucket
    const int sb = blockIdx.x & 3;         // 256-row sub-bucket
    const int s = start[bm];
    const int e = start[bm + 1];
    const int lane = tid & 63;

    const int g = tid >> 4;                // 0..63 (16-lane row group)
    const int l16 = tid & 15;
    const vf4* x4 = (const vf4*)x;
    vf4* out4 = (vf4*)out;
    const long long rbase = (long long)bm * RPM + (long long)sb * RPB;

    if (tid == 0) ns_sh = 0;
    if (tid < RPB) cnt[tid] = 0;
    __syncthreads();

    // a) stream run, wave-ballot filter own slice into ed[] + row hist
    const long long* pk = (const long long*)packed;
    for (int ib = s; ib < e; ib += NTHR) {
        int i = ib + tid;
        bool m = false;
        int px = 0, py = 0;
        if (i < e) {
            long long pv = __builtin_nontemporal_load(&pk[i]);
            px = (int)pv;
            py = (int)(pv >> 32);
            m = (((px >> 27) & 3) == sb);
        }
        unsigned long long mk = __ballot(m);
        if (mk) {
            int leader = __builtin_ctzll(mk);
            int base = 0;
            if (lane == leader) base = atomicAdd(&ns_sh, __popcll(mk));
            base = __shfl(base, leader);
            if (m) {
                int d = base + __popcll(mk & ((1ull << lane) - 1));
                if (d < CAP) ed[d] = make_int2(px, py);
                atomicAdd(&cnt[(px >> 19) & 255], 1);
            }
        }
    }
    __syncthreads();
    const int nf = ns_sh;

    if (nf <= CAP) {
        // b) inclusive scan over 256 row counts
        if (tid < RPB) sc[tid] = cnt[tid];
        __syncthreads();
        for (int off = 1; off < RPB; off <<= 1) {
            int t = 0;
            if (tid < RPB && tid >= off) t = sc[tid - off];
            __syncthreads();
            if (tid < RPB) sc[tid] += t;
            __syncthreads();
        }
        if (tid < RPB) cur[tid] = (tid > 0) ? sc[tid - 1] : 0;
        __syncthreads();

        // c) inverse permutation (sorted pos -> staged idx)
        for (int i = tid; i < nf; i += NTHR) {
            int lr = (ed[i].x >> 19) & 255;
            int d = atomicAdd(&cur[lr], 1);
            inv[d] = (unsigned short)i;
        }
        __syncthreads();

        // d) register-accumulate reduce: 4 passes x 64 rows, 8-wide MLP
#pragma unroll
        for (int p = 0; p < 4; p++) {
            int r = p * 64 + g;
            int rs = r ? sc[r - 1] : 0;
            int re = sc[r];
            vf4 a = (vf4)0.f;
            int j = rs;
            // head: advance to 8-aligned inv offset (16B-aligned ds_read)
            int ja = (rs + 7) & ~7;
            if (ja > re) ja = re;
            for (; j < ja; j++) {
                int2 e0 = ed[inv[j]];
                a += __int_as_float(e0.y) * x4[(size_t)(e0.x & 0x7FFFF) * 16 + l16];
            }
            // body: 8 edges per iter — 1 ds_read_b128 -> 8 ed -> 8 x-loads
            for (; j + 8 <= re; j += 8) {
                uint4 iv = *(const uint4*)(inv + j);
                int id[8];
                id[0] = iv.x & 0xffff; id[1] = iv.x >> 16;
                id[2] = iv.y & 0xffff; id[3] = iv.y >> 16;
                id[4] = iv.z & 0xffff; id[5] = iv.z >> 16;
                id[6] = iv.w & 0xffff; id[7] = iv.w >> 16;
                int2 ee[8];
#pragma unroll
                for (int q = 0; q < 8; q++) ee[q] = ed[id[q]];
                vf4 xv[8];
#pragma unroll
                for (int q = 0; q < 8; q++)
                    xv[q] = x4[(size_t)(ee[q].x & 0x7FFFF) * 16 + l16];
#pragma unroll
                for (int q = 0; q < 8; q++)
                    a += __int_as_float(ee[q].y) * xv[q];
            }
            // tail
            for (; j < re; j++) {
                int2 e0 = ed[inv[j]];
                a += __int_as_float(e0.y) * x4[(size_t)(e0.x & 0x7FFFF) * 16 + l16];
            }
            long long rg = rbase + r;
            if (rg < n_nodes)
                __builtin_nontemporal_store(a, &out4[rg * 16 + l16]);
        }
    } else {
        // overflow: scan-filter the run from global (rare correctness path)
#pragma unroll
        for (int p = 0; p < 4; p++) {
            int r = p * 64 + g;
            int lt = (sb << 8) | r;        // target lrow10
            vf4 a = (vf4)0.f;
            for (int i = s; i < e; i++) {
                int2 e0 = packed[i];
                if (((e0.x >> 19) & 1023) == lt) {
                    vf4 x0 = x4[(size_t)(e0.x & 0x7FFFF) * 16 + l16];
                    a += __int_as_float(e0.y) * x0;
                }
            }
            long long rg = rbase + r;
            if (rg < n_nodes)
                __builtin_nontemporal_store(a, &out4[rg * 16 + l16]);
        }
    }
}

// ---------------- fallback (round-1 atomic version) ----------------
__global__ __launch_bounds__(256)
void graphconv_scatter(const float* __restrict__ x, const float* __restrict__ edge_vals,
                       const int* __restrict__ row, const int* __restrict__ col,
                       float* __restrict__ out, int n_edges) {
    int tid = blockIdx.x * blockDim.x + threadIdx.x;
    int lane16 = tid & 15;
    int e = tid >> 4;
    if (e >= n_edges) return;
    int r = row[e];
    int c = col[e];
    float v = edge_vals[e];
    const float4* xs = (const float4*)(x + (size_t)c * D_FEAT);
    float4 xv = xs[lane16];
    float* o = out + (size_t)r * D_FEAT + lane16 * 4;
    atomicAdd(o + 0, v * xv.x);
    atomicAdd(o + 1, v * xv.y);
    atomicAdd(o + 2, v * xv.z);
    atomicAdd(o + 3, v * xv.w);
}

extern "C" void kernel_launch(void* const* d_in, const int* in_sizes, int n_in,
                              void* d_out, int out_size, void* d_ws, size_t ws_size,
                              hipStream_t stream) {
    const float* x         = (const float*)d_in[0];
    const float* edge_vals = (const float*)d_in[1];
    const int*   row       = (const int*)d_in[2];
    const int*   col       = (const int*)d_in[3];
    float* out = (float*)d_out;

    const int n_nodes = in_sizes[0] / D_FEAT;
    const int n_edges = in_sizes[1];
    const int kb = (n_nodes + RPM - 1) >> BKT_SHIFT;

    // ---- workspace layout ----
    size_t off = 0;
    auto alloc = [&](size_t bytes) {
        size_t p = off;
        off += (bytes + 255) & ~size_t(255);
        return p;
    };
    size_t o_start    = alloc((size_t)(kb + 1) * sizeof(int));
    size_t o_gcursor  = alloc((size_t)kb * sizeof(int));
    size_t o_cnt      = alloc((size_t)kb * sizeof(int));
    size_t o_packed   = alloc((size_t)n_edges * sizeof(int2));

    if (kb > MAX_BKT || n_nodes > (1 << 19) || off > ws_size) {
        hipMemsetAsync(d_out, 0, (size_t)out_size * sizeof(float), stream);
        long long total_threads = (long long)n_edges * 16;
        int grid = (int)((total_threads + 255) / 256);
        graphconv_scatter<<<grid, 256, 0, stream>>>(x, edge_vals, row, col, out, n_edges);
        return;
    }

    char* wsb = (char*)d_ws;
    int*  start     = (int*)(wsb + o_start);
    int*  gcursor   = (int*)(wsb + o_gcursor);
    int*  cnt_g     = (int*)(wsb + o_cnt);
    int2* packed    = (int2*)(wsb + o_packed);

    const int nblks = (n_edges + TILE - 1) / TILE;

    hipMemsetAsync(cnt_g, 0, (size_t)kb * sizeof(int), stream);
    hist_kernel<<<nblks, NTHR, 0, stream>>>(row, cnt_g, n_edges, kb);
    scan_kernel<<<1, 256, 0, stream>>>(cnt_g, start, gcursor, kb);
    bin_kernel<<<nblks, NTHR, 0, stream>>>(row, col, edge_vals, gcursor,
                                           packed, n_edges, kb);
    sort_reduce<<<kb * 4, NTHR, 0, stream>>>(x, packed, start, out, n_nodes);
}